// Round 5
// baseline (9856.675 us; speedup 1.0000x reference)
//
#include <hip/hip_runtime.h>
#include <hip/hip_fp16.h>

// HGNN: 3 layers of e = act(A @ (A^T @ e)), N=150000, E=4.8M, D=64.
// Column-sweep tiled SpMM: 512 destination groups x 293 rows; per group,
// edges sorted by source phase (src>>10, 147 phases). All 512 blocks
// (2/CU, zero tail) sweep phases together -> GPU-wide gather window
// ~128KB stays L2-resident; x-table fetched ~once per XCD per SpMM
// (154MB fabric vs ~490MB random-miss). Full 128B fp16 x-rows = one
// cache line per visit. Output accumulated in LDS fp32 via ds_add_f32,
// written once as fp16. Final layer: x1/64 prescale (LN scale-invariant,
// avoids fp16 overflow of z~1.4e5) -> fp16 z -> LN+residual kernel.

#define NTOT 150000
#define NE   4800000
#define DD   64
#define NG   512            // destination groups per direction
#define RPG  293            // rows per group (512*293 = 150016)
#define NBLK 512            // build blocks
#define EPB  9375           // edges per build block
#define ACCW 65             // LDS row stride (bank spread: 65 mod 32 = 1)

typedef unsigned int nt_u2 __attribute__((ext_vector_type(2)));
typedef int          nt_i4 __attribute__((ext_vector_type(4)));

// ---------- phase 1: per-block group histogram (no global atomics) ----------
__global__ __launch_bounds__(256) void k_hist(const int* __restrict__ rows,
                                              const int* __restrict__ cols,
                                              int* __restrict__ histR,
                                              int* __restrict__ histC) {
    __shared__ int hR[NG], hC[NG];
    const int tid = threadIdx.x, blk = blockIdx.x;
    for (int i = tid; i < NG; i += 256) { hR[i] = 0; hC[i] = 0; }
    __syncthreads();
    const int e0 = blk * EPB;
    const int e1 = min(NE, e0 + EPB);
    for (int e = e0 + tid; e < e1; e += 256) {
        atomicAdd(&hR[rows[e] / RPG], 1);
        atomicAdd(&hC[cols[e] / RPG], 1);
    }
    __syncthreads();
    for (int i = tid; i < NG; i += 256) {
        histR[i * NBLK + blk] = hR[i];
        histC[i * NBLK + blk] = hC[i];
    }
}

// ---------- phase 2: exclusive scan of [group][block] + group bounds ----------
__global__ __launch_bounds__(1024) void k_scan2(int* __restrict__ hR, int* __restrict__ hC,
                                                int* __restrict__ bbR, int* __restrict__ bbC) {
    __shared__ int wtot[16], wexcl[16];
    __shared__ int ctot;
    int* a  = blockIdx.x ? hC  : hR;
    int* bb = blockIdx.x ? bbC : bbR;
    const int n = NG * NBLK;
    const int tid  = threadIdx.x;
    const int lane = tid & 63, wv = tid >> 6;
    int carry = 0;
    for (int base = 0; base < n; base += 1024) {
        const int i = base + tid;
        const int v = (i < n) ? a[i] : 0;
        int s = v;
        #pragma unroll
        for (int off = 1; off < 64; off <<= 1) {
            int t = __shfl_up(s, off);
            if (lane >= off) s += t;
        }
        if (lane == 63) wtot[wv] = s;
        __syncthreads();
        if (tid == 0) {
            int run = 0;
            #pragma unroll
            for (int w = 0; w < 16; ++w) { wexcl[w] = run; run += wtot[w]; }
            ctot = run;
        }
        __syncthreads();
        if (i < n) a[i] = carry + wexcl[wv] + (s - v);
        carry += ctot;
        __syncthreads();
    }
    for (int i = tid; i <= NG; i += 1024) bb[i] = (i < NG) ? a[i * NBLK] : NE;
}

// ---------- phase 3: bin edges into group-contiguous ranges ----------
__global__ __launch_bounds__(256) void k_bin(const int* __restrict__ rows,
                                             const int* __restrict__ cols,
                                             const float* __restrict__ vals,
                                             const int* __restrict__ histR,
                                             const int* __restrict__ histC,
                                             int2* __restrict__ binR,
                                             int2* __restrict__ binC) {
    __shared__ int cR[NG], cC[NG];
    const int tid = threadIdx.x, blk = blockIdx.x;
    for (int i = tid; i < NG; i += 256) {
        cR[i] = histR[i * NBLK + blk];
        cC[i] = histC[i * NBLK + blk];
    }
    __syncthreads();
    const int e0 = blk * EPB;
    const int e1 = min(NE, e0 + EPB);
    for (int e = e0 + tid; e < e1; e += 256) {
        const int r = rows[e], c = cols[e];
        const int vb = __float_as_int(vals[e]);
        const int gr = r / RPG, lr = r - gr * RPG;
        int p = atomicAdd(&cR[gr], 1);
        int2 pr; pr.x = (lr << 18) | c; pr.y = vb;   // payload: local dst | src
        binR[p] = pr;
        const int gc = c / RPG, lc = c - gc * RPG;
        int q = atomicAdd(&cC[gc], 1);
        int2 pc; pc.x = (lc << 18) | r; pc.y = vb;
        binC[q] = pc;
    }
}

// ---------- phase 4: per-group counting sort by source phase (src>>10) ----------
__global__ __launch_bounds__(1024) void k_sortp(const int* __restrict__ bbR,
                                                const int2* __restrict__ binR,
                                                int2* __restrict__ edR,
                                                const int* __restrict__ bbC,
                                                const int2* __restrict__ binC,
                                                int2* __restrict__ edC) {
    __shared__ int hist[1024];
    __shared__ int cur[1024];
    __shared__ int wtot[16], wexcl[16];
    const int tid = threadIdx.x;
    const int lane = tid & 63, wv = tid >> 6;
    const int dir = (blockIdx.x >= NG) ? 1 : 0;
    const int b = blockIdx.x - dir * NG;
    const int*  bb  = dir ? bbC  : bbR;
    const int2* bin = dir ? binC : binR;
    int2*       out = dir ? edC  : edR;
    const int ebase = bb[b];
    const int eend  = bb[b + 1];
    hist[tid] = 0;
    __syncthreads();
    for (int i = ebase + tid; i < eend; i += 1024)
        atomicAdd(&hist[(bin[i].x & 0x3FFFF) >> 10], 1);
    __syncthreads();
    const int v = hist[tid];
    int s = v;
    #pragma unroll
    for (int off = 1; off < 64; off <<= 1) { int t = __shfl_up(s, off); if (lane >= off) s += t; }
    if (lane == 63) wtot[wv] = s;
    __syncthreads();
    if (tid == 0) { int run = 0; for (int w = 0; w < 16; ++w) { wexcl[w] = run; run += wtot[w]; } }
    __syncthreads();
    cur[tid] = ebase + wexcl[wv] + (s - v);
    __syncthreads();
    for (int i = ebase + tid; i < eend; i += 1024) {
        const int2 ed = bin[i];
        const int key = (ed.x & 0x3FFFF) >> 10;
        const int pos = atomicAdd(&cur[key], 1);
        out[pos] = ed;
    }
}

// ---------- ego fp32 -> fp16 full-row (128B rows) ----------
__global__ __launch_bounds__(256) void k_cvt(const float4* __restrict__ x,
                                             int4* __restrict__ y) {
    const int i = blockIdx.x * 256 + threadIdx.x;   // over NTOT*8 int4 units
    if (i >= NTOT * 8) return;
    const int r = i >> 3, ch = i & 7;
    const float4 f0 = x[r * 16 + ch * 2];
    const float4 f1 = x[r * 16 + ch * 2 + 1];
    int4 o;
    __half2* oh = (__half2*)&o;
    oh[0] = __floats2half2_rn(f0.x, f0.y);
    oh[1] = __floats2half2_rn(f0.z, f0.w);
    oh[2] = __floats2half2_rn(f1.x, f1.y);
    oh[3] = __floats2half2_rn(f1.z, f1.w);
    y[i] = o;
}

// ---------- column-sweep tiled SpMM: LDS fp32 accum, phase-sorted edges ----------
// MODE 0: plain -> half; MODE 1: LeakyReLU(0.5) -> half; MODE 2: x(1/64) -> half
template <int MODE>
__global__ __launch_bounds__(1024) void k_spmm_t(const int* __restrict__ bb,
                                                 const int2* __restrict__ edges,
                                                 const int4* __restrict__ X,
                                                 int4* __restrict__ Y) {
    __shared__ float acc[RPG * ACCW];   // 76,180 B
    const int tid = threadIdx.x;
    for (int i = tid; i < RPG * ACCW; i += 1024) acc[i] = 0.f;
    __syncthreads();
    const int gb = blockIdx.x;
    const int s = bb[gb], e = bb[gb + 1];
    const int w = tid >> 6, lane = tid & 63;
    const int g = lane >> 3, ch = lane & 7;   // 8 edges/wave-iter, 16B chunk each
    for (int ib = s + w * 8; ib < e; ib += 128) {
        const int idx = ib + g;
        int2 ed;
        if (idx < e) {
            const nt_u2 u = __builtin_nontemporal_load((const nt_u2*)(edges + idx));
            ed.x = (int)u.x; ed.y = (int)u.y;
        } else { ed.x = 0; ed.y = 0; }       // wv=0 -> harmless add of 0
        const int   c  = ed.x & 0x3FFFF;
        const int   lr = ((unsigned)ed.x) >> 18;
        const float wv = __int_as_float(ed.y);
        const int4 q = X[c * 8 + ch];        // 16B of the 128B source row
        const __half2* h2 = (const __half2*)&q;
        float* ap = &acc[lr * ACCW + ch * 8];
        #pragma unroll
        for (int k = 0; k < 4; ++k) {
            const float2 f = __half22float2(h2[k]);
            atomicAdd(ap + 2 * k,     wv * f.x);
            atomicAdd(ap + 2 * k + 1, wv * f.y);
        }
    }
    __syncthreads();
    const int r0 = gb * RPG;
    for (int i = tid; i < RPG * 8; i += 1024) {
        const int lr = i >> 3, c8 = i & 7;
        if (r0 + lr >= NTOT) continue;
        float v[8];
        #pragma unroll
        for (int k = 0; k < 8; ++k) {
            float t = acc[lr * ACCW + c8 * 8 + k];
            if (MODE == 1) t = t > 0.f ? t : 0.5f * t;
            if (MODE == 2) t *= 0.015625f;   // LN-invariant prescale
            v[k] = t;
        }
        int4 o;
        __half2* oh = (__half2*)&o;
        #pragma unroll
        for (int k = 0; k < 4; ++k) oh[k] = __floats2half2_rn(v[2 * k], v[2 * k + 1]);
        __builtin_nontemporal_store(*(const nt_i4*)&o,
                                    (nt_i4*)(Y + (size_t)(r0 + lr) * 8 + c8));
    }
}

// ---------- LN + residual on fp16 full-row z (z prescaled by 1/64) ----------
__global__ __launch_bounds__(256) void k_lnz(const int4* __restrict__ z,
                                             const float* __restrict__ gamma,
                                             const float* __restrict__ beta,
                                             const float* __restrict__ ego,
                                             float* __restrict__ out) {
    const int tid = threadIdx.x;
    const int ch = tid & 7;
    const int r = blockIdx.x * 32 + (tid >> 3);
    if (r >= NTOT) return;
    const int4 zq = z[(size_t)r * 8 + ch];
    const __half2* h = (const __half2*)&zq;
    float f[8];
    #pragma unroll
    for (int k = 0; k < 4; ++k) {
        const float2 t = __half22float2(h[k]);
        f[2 * k] = t.x; f[2 * k + 1] = t.y;
    }
    float s1 = 0.f;
    #pragma unroll
    for (int k = 0; k < 8; ++k) s1 += f[k];
    #pragma unroll
    for (int off = 1; off < 8; off <<= 1) s1 += __shfl_xor(s1, off);
    const float mu = s1 * (1.f / 64.f);
    float q2 = 0.f;
    #pragma unroll
    for (int k = 0; k < 8; ++k) { f[k] -= mu; q2 += f[k] * f[k]; }
    #pragma unroll
    for (int off = 1; off < 8; off <<= 1) q2 += __shfl_xor(q2, off);
    const float rs = rsqrtf(q2 * (1.f / 64.f) + 2.44140625e-09f);  // eps*(1/64)^2
    const float4* g4 = (const float4*)gamma;
    const float4* b4 = (const float4*)beta;
    const float4* e4 = (const float4*)ego + (size_t)r * 16;
    float4*       o4 = (float4*)out + (size_t)r * 16;
    #pragma unroll
    for (int half = 0; half < 2; ++half) {
        const float4 gg = g4[ch * 2 + half];
        const float4 bbv = b4[ch * 2 + half];
        const float4 ee = e4[ch * 2 + half];
        float4 o;
        o.x = f[4 * half + 0] * rs * gg.x + bbv.x + ee.x;
        o.y = f[4 * half + 1] * rs * gg.y + bbv.y + ee.y;
        o.z = f[4 * half + 2] * rs * gg.z + bbv.z + ee.z;
        o.w = f[4 * half + 3] * rs * gg.w + bbv.w + ee.w;
        o4[ch * 2 + half] = o;
    }
}

// ---------- fallback: atomic push (only if ws too small) ----------
__global__ __launch_bounds__(256) void k_push(const int* __restrict__ src_idx,
                                              const int* __restrict__ dst_idx,
                                              const float* __restrict__ vals,
                                              const float* __restrict__ x,
                                              float* __restrict__ y) {
    int gid  = blockIdx.x * 256 + threadIdx.x;
    int e    = gid >> 6;
    int lane = gid & 63;
    if (e >= NE) return;
    atomicAdd(&y[dst_idx[e] * DD + lane], vals[e] * x[src_idx[e] * DD + lane]);
}

__global__ __launch_bounds__(256) void k_leaky(float* __restrict__ x, int n) {
    int i = blockIdx.x * 256 + threadIdx.x;
    if (i < n) { float v = x[i]; x[i] = v > 0.f ? v : 0.5f * v; }
}

__global__ __launch_bounds__(256) void k_lnf(const float* __restrict__ z,
                                             const float* __restrict__ gamma,
                                             const float* __restrict__ beta,
                                             const float* __restrict__ ego,
                                             float* __restrict__ out) {
    int gid  = blockIdx.x * 256 + threadIdx.x;
    int wid  = gid >> 6;
    int lane = threadIdx.x & 63;
    if (wid >= NTOT) return;
    float v = z[wid * DD + lane];
    float sum = v;
    #pragma unroll
    for (int off = 32; off; off >>= 1) sum += __shfl_xor(sum, off);
    float mu = sum * (1.f / 64.f);
    float d  = v - mu;
    float vs = d * d;
    #pragma unroll
    for (int off = 32; off; off >>= 1) vs += __shfl_xor(vs, off);
    float rs = rsqrtf(vs * (1.f / 64.f) + 1e-5f);
    out[wid * DD + lane] = d * rs * gamma[lane] + beta[lane] + ego[wid * DD + lane];
}

extern "C" void kernel_launch(void* const* d_in, const int* in_sizes, int n_in,
                              void* d_out, int out_size, void* d_ws, size_t ws_size,
                              hipStream_t stream) {
    const float* ego   = (const float*)d_in[0];
    const float* vals  = (const float*)d_in[1];
    const float* gamma = (const float*)d_in[2];
    const float* beta  = (const float*)d_in[3];
    const int*   rows  = (const int*)d_in[4];
    const int*   cols  = (const int*)d_in[5];
    float* out = (float*)d_out;

    const size_t SEG   = (size_t)NE * 8;          // 38,400,000 (region stride)
    const size_t SMETA = 600064;
    const size_t NEED  = 3 * SEG + 2 * SMETA + 1280;

    if (ws_size >= NEED) {
        char* w = (char*)d_ws;
        int2* edR  = (int2*)w;                     // SEG0: final R edges (38.4MB)
        int2* edC  = (int2*)(w + SEG);             // SEG1: final C edges
        int2* binR = (int2*)(w + 2 * SEG);         // SEG2: bin scratch R
        int2* binC = (int2*)d_out;                 // d_out: bin scratch C
        int* histR = (int*)w;                      // aliases edR (dead until sortp)
        int* histC = (int*)(w + SEG);              // aliases edC
        int* bbR   = (int*)(w + 3 * SEG);          // group bounds (513 ints each)
        int* bbC   = bbR + (NG + 1);
        // fp16 feature tables (19.2MB each) alias dead binR region after build
        int4* B1 = (int4*)(w + 2 * SEG);
        int4* B2 = (int4*)(w + 2 * SEG + SEG / 2);
        int4* EG = (int4*)d_out;                   // ego fp16 over dead binC

        k_hist <<<NBLK, 256, 0, stream>>>(rows, cols, histR, histC);
        k_scan2<<<2, 1024, 0, stream>>>(histR, histC, bbR, bbC);
        k_bin  <<<NBLK, 256, 0, stream>>>(rows, cols, vals, histR, histC, binR, binC);
        k_sortp<<<2 * NG, 1024, 0, stream>>>(bbR, binR, edR, bbC, binC, edC);
        k_cvt  <<<(NTOT * 8 + 255) / 256, 256, 0, stream>>>((const float4*)ego, EG);

        k_spmm_t<0><<<NG, 1024, 0, stream>>>(bbC, edC, EG, B1);   // A^T e0
        k_spmm_t<1><<<NG, 1024, 0, stream>>>(bbR, edR, B1, B2);   // leaky(A t)
        k_spmm_t<0><<<NG, 1024, 0, stream>>>(bbC, edC, B2, B1);
        k_spmm_t<1><<<NG, 1024, 0, stream>>>(bbR, edR, B1, B2);
        k_spmm_t<0><<<NG, 1024, 0, stream>>>(bbC, edC, B2, B1);
        k_spmm_t<2><<<NG, 1024, 0, stream>>>(bbR, edR, B1, B2);   // z/64 -> fp16
        k_lnz  <<<(NTOT + 31) / 32, 256, 0, stream>>>(B2, gamma, beta, ego, out);
    } else {
        const size_t FEAT_BYTES = (size_t)NTOT * DD * 4;
        float* B1 = (float*)d_ws;
        float* B2 = out;
        const int GRID_P = NE / 4;
        const int GRID_N = (NTOT * DD) / 256;
        const float* e = ego;
        for (int layer = 0; layer < 3; ++layer) {
            hipMemsetAsync(B1, 0, FEAT_BYTES, stream);
            k_push<<<GRID_P, 256, 0, stream>>>(rows, cols, vals, e, B1);
            hipMemsetAsync(B2, 0, FEAT_BYTES, stream);
            k_push<<<GRID_P, 256, 0, stream>>>(cols, rows, vals, B1, B2);
            if (layer < 2) {
                k_leaky<<<GRID_N, 256, 0, stream>>>(B2, NTOT * DD);
                e = B2;
            } else {
                k_lnf<<<GRID_N, 256, 0, stream>>>(B2, gamma, beta, ego, out);
            }
        }
    }
}

// Round 6
// 3168.941 us; speedup vs baseline: 3.1104x; 3.1104x over previous
//
#include <hip/hip_runtime.h>
#include <hip/hip_fp16.h>

// HGNN: 3 layers of e = act(A @ (A^T @ e)), N=150000, E=4.8M, D=64.
// Column-sweep register-pull SpMM: 586 groups x 256 dst rows. Per group,
// edges sorted by (owner_row, src_phase) (phase = src>>12, 37 windows of
// 512KB). Block = 1024 thr = 256 row-owners x 4 dim-chunks; each thread
// accumulates its row's 16 dims in REGISTERS (no LDS atomics - round-5
// post-mortem: 64 LDS atomics/edge = 0.32/cycle/CU serialization wall).
// All blocks sweep source phases together -> gather window L2-resident
// (round-5 verified: FETCH 262MB vs 860MB unswept). Full fp32 edge vals.
// Final layer: x1/64 prescale (LN scale-invariant; avoids fp16 overflow
// of z~1.4e5) -> fp16 z -> LN+residual kernel.

#define NTOT 150000
#define NE   4800000
#define DD   64
#define NG   586            // destination groups (256 rows each; 586*256=150016)
#define RPG  256
#define NBLK 512            // build blocks
#define EPB  9375           // edges per build block
#define NPH  37             // source phases (src>>12, 150000>>12 = 36)
#define BINS (RPG * NPH)    // 9472 sort bins per group

typedef int nt_i4 __attribute__((ext_vector_type(4)));

// ---------- phase 1: per-block group histogram (no global atomics) ----------
__global__ __launch_bounds__(256) void k_hist(const int* __restrict__ rows,
                                              const int* __restrict__ cols,
                                              int* __restrict__ histR,
                                              int* __restrict__ histC) {
    __shared__ int hR[NG], hC[NG];
    const int tid = threadIdx.x, blk = blockIdx.x;
    for (int i = tid; i < NG; i += 256) { hR[i] = 0; hC[i] = 0; }
    __syncthreads();
    const int e0 = blk * EPB;
    const int e1 = min(NE, e0 + EPB);
    for (int e = e0 + tid; e < e1; e += 256) {
        atomicAdd(&hR[rows[e] >> 8], 1);
        atomicAdd(&hC[cols[e] >> 8], 1);
    }
    __syncthreads();
    for (int i = tid; i < NG; i += 256) {
        histR[i * NBLK + blk] = hR[i];
        histC[i * NBLK + blk] = hC[i];
    }
}

// ---------- phase 2: exclusive scan of [group][block] + group bounds ----------
__global__ __launch_bounds__(1024) void k_scan2(int* __restrict__ hR, int* __restrict__ hC,
                                                int* __restrict__ bbR, int* __restrict__ bbC) {
    __shared__ int wtot[16], wexcl[16];
    __shared__ int ctot;
    int* a  = blockIdx.x ? hC  : hR;
    int* bb = blockIdx.x ? bbC : bbR;
    const int n = NG * NBLK;
    const int tid  = threadIdx.x;
    const int lane = tid & 63, wv = tid >> 6;
    int carry = 0;
    for (int base = 0; base < n; base += 1024) {
        const int i = base + tid;
        const int v = (i < n) ? a[i] : 0;
        int s = v;
        #pragma unroll
        for (int off = 1; off < 64; off <<= 1) {
            int t = __shfl_up(s, off);
            if (lane >= off) s += t;
        }
        if (lane == 63) wtot[wv] = s;
        __syncthreads();
        if (tid == 0) {
            int run = 0;
            #pragma unroll
            for (int w = 0; w < 16; ++w) { wexcl[w] = run; run += wtot[w]; }
            ctot = run;
        }
        __syncthreads();
        if (i < n) a[i] = carry + wexcl[wv] + (s - v);
        carry += ctot;
        __syncthreads();
    }
    for (int i = tid; i <= NG; i += 1024) bb[i] = (i < NG) ? a[i * NBLK] : NE;
}

// ---------- phase 3: bin edges into group-contiguous ranges ----------
__global__ __launch_bounds__(256) void k_bin(const int* __restrict__ rows,
                                             const int* __restrict__ cols,
                                             const float* __restrict__ vals,
                                             const int* __restrict__ histR,
                                             const int* __restrict__ histC,
                                             int2* __restrict__ binR,
                                             int2* __restrict__ binC) {
    __shared__ int cR[NG], cC[NG];
    const int tid = threadIdx.x, blk = blockIdx.x;
    for (int i = tid; i < NG; i += 256) {
        cR[i] = histR[i * NBLK + blk];
        cC[i] = histC[i * NBLK + blk];
    }
    __syncthreads();
    const int e0 = blk * EPB;
    const int e1 = min(NE, e0 + EPB);
    for (int e = e0 + tid; e < e1; e += 256) {
        const int r = rows[e], c = cols[e];
        const int vb = __float_as_int(vals[e]);
        int p = atomicAdd(&cR[r >> 8], 1);
        int2 pr; pr.x = ((r & 255) << 18) | c; pr.y = vb;   // local dst | src
        binR[p] = pr;
        int q = atomicAdd(&cC[c >> 8], 1);
        int2 pc; pc.x = ((c & 255) << 18) | r; pc.y = vb;
        binC[q] = pc;
    }
}

// ---------- phase 4: per-group sort by (owner row, src phase) + owner starts ----------
__global__ __launch_bounds__(1024) void k_sortp(const int* __restrict__ bbR,
                                                const int2* __restrict__ binR,
                                                int2* __restrict__ edR,
                                                unsigned short* __restrict__ ostR,
                                                const int* __restrict__ bbC,
                                                const int2* __restrict__ binC,
                                                int2* __restrict__ edC,
                                                unsigned short* __restrict__ ostC) {
    __shared__ int cnt[BINS];
    __shared__ int wtot[16], wexcl[16];
    const int tid = threadIdx.x;
    const int lane = tid & 63, wv = tid >> 6;
    const int dir = (blockIdx.x >= NG) ? 1 : 0;
    const int b = blockIdx.x - dir * NG;
    const int*  bb  = dir ? bbC  : bbR;
    const int2* bin = dir ? binC : binR;
    int2*       ed  = dir ? edC  : edR;
    unsigned short* ost = dir ? ostC : ostR;
    const int ebase = bb[b];
    const int eend  = bb[b + 1];
    for (int i = tid; i < BINS; i += 1024) cnt[i] = 0;
    __syncthreads();
    for (int i = ebase + tid; i < eend; i += 1024) {
        const int x = bin[i].x;
        atomicAdd(&cnt[((x >> 18) & 255) * NPH + ((x & 0x3FFFF) >> 12)], 1);
    }
    __syncthreads();
    // exclusive scan over BINS: 10 bins/thread serial + block scan
    int loc[10];
    int s = 0;
    #pragma unroll
    for (int k = 0; k < 10; ++k) {
        const int idx = tid * 10 + k;
        const int v = (idx < BINS) ? cnt[idx] : 0;
        loc[k] = s; s += v;
    }
    int ps = s;
    #pragma unroll
    for (int off = 1; off < 64; off <<= 1) { int t = __shfl_up(ps, off); if (lane >= off) ps += t; }
    if (lane == 63) wtot[wv] = ps;
    __syncthreads();
    if (tid == 0) { int run = 0; for (int w = 0; w < 16; ++w) { wexcl[w] = run; run += wtot[w]; } }
    __syncthreads();
    const int base = wexcl[wv] + (ps - s);
    __syncthreads();
    #pragma unroll
    for (int k = 0; k < 10; ++k) {
        const int idx = tid * 10 + k;
        if (idx < BINS) cnt[idx] = base + loc[k];
    }
    __syncthreads();
    if (tid < RPG) ost[b * RPG + tid] = (unsigned short)cnt[tid * NPH];
    __syncthreads();
    for (int i = ebase + tid; i < eend; i += 1024) {
        const int2 edv = bin[i];
        const int key = ((edv.x >> 18) & 255) * NPH + ((edv.x & 0x3FFFF) >> 12);
        const int pos = ebase + atomicAdd(&cnt[key], 1);
        ed[pos] = edv;
    }
}

// ---------- ego fp32 -> fp16 full-row (128B rows) ----------
__global__ __launch_bounds__(256) void k_cvt(const float4* __restrict__ x,
                                             int4* __restrict__ y) {
    const int i = blockIdx.x * 256 + threadIdx.x;   // over NTOT*8 int4 units
    if (i >= NTOT * 8) return;
    const int r = i >> 3, ch = i & 7;
    const float4 f0 = x[r * 16 + ch * 2];
    const float4 f1 = x[r * 16 + ch * 2 + 1];
    int4 o;
    __half2* oh = (__half2*)&o;
    oh[0] = __floats2half2_rn(f0.x, f0.y);
    oh[1] = __floats2half2_rn(f0.z, f0.w);
    oh[2] = __floats2half2_rn(f1.x, f1.y);
    oh[3] = __floats2half2_rn(f1.z, f1.w);
    y[i] = o;
}

// ---------- register-pull SpMM, phase-swept, thread-per-(row, 16 dims) ----------
// MODE 0: plain -> half; MODE 1: LeakyReLU(0.5) -> half; MODE 2: x(1/64) -> half
#define FMA16(QA, QB, W) { \
    const __half2* h2a = (const __half2*)&(QA); \
    const __half2* h2b = (const __half2*)&(QB); \
    _Pragma("unroll") \
    for (int k = 0; k < 4; ++k) { \
        const float2 fa = __half22float2(h2a[k]); \
        a[2 * k]     = fmaf((W), fa.x, a[2 * k]); \
        a[2 * k + 1] = fmaf((W), fa.y, a[2 * k + 1]); \
        const float2 fb = __half22float2(h2b[k]); \
        a[8 + 2 * k]     = fmaf((W), fb.x, a[8 + 2 * k]); \
        a[8 + 2 * k + 1] = fmaf((W), fb.y, a[8 + 2 * k + 1]); \
    } }

template <int MODE>
__global__ __launch_bounds__(1024) void k_spmm_r(const int* __restrict__ bb,
                                                 const unsigned short* __restrict__ ost,
                                                 const int2* __restrict__ edges,
                                                 const int4* __restrict__ X,
                                                 int4* __restrict__ Y) {
    const int tid = threadIdx.x;
    const int o  = tid & 255;           // owner row within group
    const int c2 = tid >> 8;            // dim chunk (16 dims = 2 int4)
    const int gb = blockIdx.x;
    const int gbase = bb[gb];
    const int s = gbase + ost[gb * RPG + o];
    const int e = (o == 255) ? bb[gb + 1] : gbase + ost[gb * RPG + o + 1];
    float a[16];
    #pragma unroll
    for (int k = 0; k < 16; ++k) a[k] = 0.f;
    int i = s;
    for (; i + 2 <= e; i += 2) {
        const int2 u0 = edges[i];
        const int2 u1 = edges[i + 1];
        const int  s0 = u0.x & 0x3FFFF;
        const int  s1 = u1.x & 0x3FFFF;
        const float w0 = __int_as_float(u0.y);
        const float w1 = __int_as_float(u1.y);
        const int4 qa0 = X[s0 * 8 + c2 * 2];
        const int4 qb0 = X[s0 * 8 + c2 * 2 + 1];
        const int4 qa1 = X[s1 * 8 + c2 * 2];
        const int4 qb1 = X[s1 * 8 + c2 * 2 + 1];
        FMA16(qa0, qb0, w0);
        FMA16(qa1, qb1, w1);
    }
    if (i < e) {
        const int2 u = edges[i];
        const int  s0 = u.x & 0x3FFFF;
        const float w0 = __int_as_float(u.y);
        const int4 qa = X[s0 * 8 + c2 * 2];
        const int4 qb = X[s0 * 8 + c2 * 2 + 1];
        FMA16(qa, qb, w0);
    }
    if (MODE == 1) {
        #pragma unroll
        for (int k = 0; k < 16; ++k) a[k] = a[k] > 0.f ? a[k] : 0.5f * a[k];
    }
    if (MODE == 2) {
        #pragma unroll
        for (int k = 0; k < 16; ++k) a[k] *= 0.015625f;   // LN-invariant prescale
    }
    const int row = gb * RPG + o;
    if (row < NTOT) {
        int4 o0, o1;
        __half2* oh0 = (__half2*)&o0;
        __half2* oh1 = (__half2*)&o1;
        #pragma unroll
        for (int k = 0; k < 4; ++k) {
            oh0[k] = __floats2half2_rn(a[2 * k], a[2 * k + 1]);
            oh1[k] = __floats2half2_rn(a[8 + 2 * k], a[8 + 2 * k + 1]);
        }
        __builtin_nontemporal_store(*(const nt_i4*)&o0, (nt_i4*)(Y + (size_t)row * 8 + c2 * 2));
        __builtin_nontemporal_store(*(const nt_i4*)&o1, (nt_i4*)(Y + (size_t)row * 8 + c2 * 2 + 1));
    }
}

// ---------- LN + residual on fp16 full-row z (z prescaled by 1/64) ----------
__global__ __launch_bounds__(256) void k_lnz(const int4* __restrict__ z,
                                             const float* __restrict__ gamma,
                                             const float* __restrict__ beta,
                                             const float* __restrict__ ego,
                                             float* __restrict__ out) {
    const int tid = threadIdx.x;
    const int ch = tid & 7;
    const int r = blockIdx.x * 32 + (tid >> 3);
    if (r >= NTOT) return;
    const int4 zq = z[(size_t)r * 8 + ch];
    const __half2* h = (const __half2*)&zq;
    float f[8];
    #pragma unroll
    for (int k = 0; k < 4; ++k) {
        const float2 t = __half22float2(h[k]);
        f[2 * k] = t.x; f[2 * k + 1] = t.y;
    }
    float s1 = 0.f;
    #pragma unroll
    for (int k = 0; k < 8; ++k) s1 += f[k];
    #pragma unroll
    for (int off = 1; off < 8; off <<= 1) s1 += __shfl_xor(s1, off);
    const float mu = s1 * (1.f / 64.f);
    float q2 = 0.f;
    #pragma unroll
    for (int k = 0; k < 8; ++k) { f[k] -= mu; q2 += f[k] * f[k]; }
    #pragma unroll
    for (int off = 1; off < 8; off <<= 1) q2 += __shfl_xor(q2, off);
    const float rs = rsqrtf(q2 * (1.f / 64.f) + 2.44140625e-09f);  // eps*(1/64)^2
    const float4* g4 = (const float4*)gamma;
    const float4* b4 = (const float4*)beta;
    const float4* e4 = (const float4*)ego + (size_t)r * 16;
    float4*       o4 = (float4*)out + (size_t)r * 16;
    #pragma unroll
    for (int half = 0; half < 2; ++half) {
        const float4 gg = g4[ch * 2 + half];
        const float4 bbv = b4[ch * 2 + half];
        const float4 ee = e4[ch * 2 + half];
        float4 o;
        o.x = f[4 * half + 0] * rs * gg.x + bbv.x + ee.x;
        o.y = f[4 * half + 1] * rs * gg.y + bbv.y + ee.y;
        o.z = f[4 * half + 2] * rs * gg.z + bbv.z + ee.z;
        o.w = f[4 * half + 3] * rs * gg.w + bbv.w + ee.w;
        o4[ch * 2 + half] = o;
    }
}

// ---------- fallback: atomic push (only if ws too small) ----------
__global__ __launch_bounds__(256) void k_push(const int* __restrict__ src_idx,
                                              const int* __restrict__ dst_idx,
                                              const float* __restrict__ vals,
                                              const float* __restrict__ x,
                                              float* __restrict__ y) {
    int gid  = blockIdx.x * 256 + threadIdx.x;
    int e    = gid >> 6;
    int lane = gid & 63;
    if (e >= NE) return;
    atomicAdd(&y[dst_idx[e] * DD + lane], vals[e] * x[src_idx[e] * DD + lane]);
}

__global__ __launch_bounds__(256) void k_leaky(float* __restrict__ x, int n) {
    int i = blockIdx.x * 256 + threadIdx.x;
    if (i < n) { float v = x[i]; x[i] = v > 0.f ? v : 0.5f * v; }
}

__global__ __launch_bounds__(256) void k_lnf(const float* __restrict__ z,
                                             const float* __restrict__ gamma,
                                             const float* __restrict__ beta,
                                             const float* __restrict__ ego,
                                             float* __restrict__ out) {
    int gid  = blockIdx.x * 256 + threadIdx.x;
    int wid  = gid >> 6;
    int lane = threadIdx.x & 63;
    if (wid >= NTOT) return;
    float v = z[wid * DD + lane];
    float sum = v;
    #pragma unroll
    for (int off = 32; off; off >>= 1) sum += __shfl_xor(sum, off);
    float mu = sum * (1.f / 64.f);
    float d  = v - mu;
    float vs = d * d;
    #pragma unroll
    for (int off = 32; off; off >>= 1) vs += __shfl_xor(vs, off);
    float rs = rsqrtf(vs * (1.f / 64.f) + 1e-5f);
    out[wid * DD + lane] = d * rs * gamma[lane] + beta[lane] + ego[wid * DD + lane];
}

extern "C" void kernel_launch(void* const* d_in, const int* in_sizes, int n_in,
                              void* d_out, int out_size, void* d_ws, size_t ws_size,
                              hipStream_t stream) {
    const float* ego   = (const float*)d_in[0];
    const float* vals  = (const float*)d_in[1];
    const float* gamma = (const float*)d_in[2];
    const float* beta  = (const float*)d_in[3];
    const int*   rows  = (const int*)d_in[4];
    const int*   cols  = (const int*)d_in[5];
    float* out = (float*)d_out;

    const size_t SEG  = (size_t)NE * 8;            // 38,400,000 (region stride)
    const size_t BBB  = (size_t)(NG + 1) * 4;      // 2,348
    const size_t OSTB = (size_t)NG * RPG * 2;      // 300,032 (ushort owner starts)
    const size_t NEED = 3 * SEG + 2 * BBB + 2 * OSTB;  // 115,804,760

    if (ws_size >= NEED) {
        char* w = (char*)d_ws;
        int2* edR  = (int2*)w;                     // SEG0: sorted R edges (38.4MB)
        int2* edC  = (int2*)(w + SEG);             // SEG1: sorted C edges
        int2* binR = (int2*)(w + 2 * SEG);         // SEG2: bin scratch R
        int2* binC = (int2*)d_out;                 // d_out: bin scratch C
        int* histR = (int*)w;                      // aliases edR (dead until sortp)
        int* histC = (int*)(w + SEG);              // aliases edC
        int* bbR   = (int*)(w + 3 * SEG);
        int* bbC   = (int*)(w + 3 * SEG + BBB);
        unsigned short* ostR = (unsigned short*)(w + 3 * SEG + 2 * BBB);
        unsigned short* ostC = (unsigned short*)(w + 3 * SEG + 2 * BBB + OSTB);
        // fp16 feature tables (19.2MB each) alias dead binR region after build
        int4* B1 = (int4*)(w + 2 * SEG);
        int4* B2 = (int4*)(w + 2 * SEG + SEG / 2);
        int4* EG = (int4*)d_out;                   // ego fp16 over dead binC

        k_hist <<<NBLK, 256, 0, stream>>>(rows, cols, histR, histC);
        k_scan2<<<2, 1024, 0, stream>>>(histR, histC, bbR, bbC);
        k_bin  <<<NBLK, 256, 0, stream>>>(rows, cols, vals, histR, histC, binR, binC);
        k_sortp<<<2 * NG, 1024, 0, stream>>>(bbR, binR, edR, ostR, bbC, binC, edC, ostC);
        k_cvt  <<<(NTOT * 8 + 255) / 256, 256, 0, stream>>>((const float4*)ego, EG);

        k_spmm_r<0><<<NG, 1024, 0, stream>>>(bbC, ostC, edC, EG, B1);   // A^T e0
        k_spmm_r<1><<<NG, 1024, 0, stream>>>(bbR, ostR, edR, B1, B2);   // leaky(A t)
        k_spmm_r<0><<<NG, 1024, 0, stream>>>(bbC, ostC, edC, B2, B1);
        k_spmm_r<1><<<NG, 1024, 0, stream>>>(bbR, ostR, edR, B1, B2);
        k_spmm_r<0><<<NG, 1024, 0, stream>>>(bbC, ostC, edC, B2, B1);
        k_spmm_r<2><<<NG, 1024, 0, stream>>>(bbR, ostR, edR, B1, B2);   // z/64 -> fp16
        k_lnz  <<<(NTOT + 31) / 32, 256, 0, stream>>>(B2, gamma, beta, ego, out);
    } else {
        const size_t FEAT_BYTES = (size_t)NTOT * DD * 4;
        float* B1 = (float*)d_ws;
        float* B2 = out;
        const int GRID_P = NE / 4;
        const int GRID_N = (NTOT * DD) / 256;
        const float* e = ego;
        for (int layer = 0; layer < 3; ++layer) {
            hipMemsetAsync(B1, 0, FEAT_BYTES, stream);
            k_push<<<GRID_P, 256, 0, stream>>>(rows, cols, vals, e, B1);
            hipMemsetAsync(B2, 0, FEAT_BYTES, stream);
            k_push<<<GRID_P, 256, 0, stream>>>(cols, rows, vals, B1, B2);
            if (layer < 2) {
                k_leaky<<<GRID_N, 256, 0, stream>>>(B2, NTOT * DD);
                e = B2;
            } else {
                k_lnf<<<GRID_N, 256, 0, stream>>>(B2, gamma, beta, ego, out);
            }
        }
    }
}

// Round 7
// 3082.127 us; speedup vs baseline: 3.1980x; 1.0282x over previous
//
#include <hip/hip_runtime.h>
#include <hip/hip_fp16.h>

// HGNN: 3 layers of e = act(A @ (A^T @ e)), N=150000, E=4.8M, D=64.
// Column-sweep register-pull SpMM: 586 groups x 256 dst rows. Per group,
// edges sorted by (owner_row, src_phase) (phase = src>>12, 37 windows).
// Block = 1024 thr = 256 row-owners x 4 dim-chunks; each thread accumulates
// its row's 16 dims in REGISTERS (round-5 lesson: LDS atomics serialize).
// QUANTILE PACING (round-6 lesson): each thread walks its edges in J=32
// quantile steps [deg*j/32, deg*(j+1)/32) so ALL lanes sit at the same
// phase fraction each step -> GPU-wide gather window ~0.6MB, L2-resident
// (round-5 measured FETCH 262MB for the synced sweep vs 1.3GB desynced).
// Final layer: x1/64 prescale (LN scale-invariant; avoids fp16 overflow
// of z~1.4e5) -> fp16 z -> LN+residual kernel.

#define NTOT 150000
#define NE   4800000
#define DD   64
#define NG   586            // destination groups (256 rows each; 586*256=150016)
#define RPG  256
#define NBLK 512            // build blocks
#define EPB  9375           // edges per build block
#define NPH  37             // source phases (src>>12)
#define BINS (RPG * NPH)    // 9472 sort bins per group

typedef int nt_i4 __attribute__((ext_vector_type(4)));

// ---------- phase 1: per-block group histogram (no global atomics) ----------
__global__ __launch_bounds__(256) void k_hist(const int* __restrict__ rows,
                                              const int* __restrict__ cols,
                                              int* __restrict__ histR,
                                              int* __restrict__ histC) {
    __shared__ int hR[NG], hC[NG];
    const int tid = threadIdx.x, blk = blockIdx.x;
    for (int i = tid; i < NG; i += 256) { hR[i] = 0; hC[i] = 0; }
    __syncthreads();
    const int e0 = blk * EPB;
    const int e1 = min(NE, e0 + EPB);
    for (int e = e0 + tid; e < e1; e += 256) {
        atomicAdd(&hR[rows[e] >> 8], 1);
        atomicAdd(&hC[cols[e] >> 8], 1);
    }
    __syncthreads();
    for (int i = tid; i < NG; i += 256) {
        histR[i * NBLK + blk] = hR[i];
        histC[i * NBLK + blk] = hC[i];
    }
}

// ---------- phase 2: exclusive scan of [group][block] + group bounds ----------
__global__ __launch_bounds__(1024) void k_scan2(int* __restrict__ hR, int* __restrict__ hC,
                                                int* __restrict__ bbR, int* __restrict__ bbC) {
    __shared__ int wtot[16], wexcl[16];
    __shared__ int ctot;
    int* a  = blockIdx.x ? hC  : hR;
    int* bb = blockIdx.x ? bbC : bbR;
    const int n = NG * NBLK;
    const int tid  = threadIdx.x;
    const int lane = tid & 63, wv = tid >> 6;
    int carry = 0;
    for (int base = 0; base < n; base += 1024) {
        const int i = base + tid;
        const int v = (i < n) ? a[i] : 0;
        int s = v;
        #pragma unroll
        for (int off = 1; off < 64; off <<= 1) {
            int t = __shfl_up(s, off);
            if (lane >= off) s += t;
        }
        if (lane == 63) wtot[wv] = s;
        __syncthreads();
        if (tid == 0) {
            int run = 0;
            #pragma unroll
            for (int w = 0; w < 16; ++w) { wexcl[w] = run; run += wtot[w]; }
            ctot = run;
        }
        __syncthreads();
        if (i < n) a[i] = carry + wexcl[wv] + (s - v);
        carry += ctot;
        __syncthreads();
    }
    for (int i = tid; i <= NG; i += 1024) bb[i] = (i < NG) ? a[i * NBLK] : NE;
}

// ---------- phase 3: bin edges into group-contiguous ranges ----------
__global__ __launch_bounds__(256) void k_bin(const int* __restrict__ rows,
                                             const int* __restrict__ cols,
                                             const float* __restrict__ vals,
                                             const int* __restrict__ histR,
                                             const int* __restrict__ histC,
                                             int2* __restrict__ binR,
                                             int2* __restrict__ binC) {
    __shared__ int cR[NG], cC[NG];
    const int tid = threadIdx.x, blk = blockIdx.x;
    for (int i = tid; i < NG; i += 256) {
        cR[i] = histR[i * NBLK + blk];
        cC[i] = histC[i * NBLK + blk];
    }
    __syncthreads();
    const int e0 = blk * EPB;
    const int e1 = min(NE, e0 + EPB);
    for (int e = e0 + tid; e < e1; e += 256) {
        const int r = rows[e], c = cols[e];
        const int vb = __float_as_int(vals[e]);
        int p = atomicAdd(&cR[r >> 8], 1);
        int2 pr; pr.x = ((r & 255) << 18) | c; pr.y = vb;   // local dst | src
        binR[p] = pr;
        int q = atomicAdd(&cC[c >> 8], 1);
        int2 pc; pc.x = ((c & 255) << 18) | r; pc.y = vb;
        binC[q] = pc;
    }
}

// ---------- phase 4: per-group sort by (owner row, src phase) + owner starts ----------
__global__ __launch_bounds__(1024) void k_sortp(const int* __restrict__ bbR,
                                                const int2* __restrict__ binR,
                                                int2* __restrict__ edR,
                                                unsigned short* __restrict__ ostR,
                                                const int* __restrict__ bbC,
                                                const int2* __restrict__ binC,
                                                int2* __restrict__ edC,
                                                unsigned short* __restrict__ ostC) {
    __shared__ int cnt[BINS];
    __shared__ int wtot[16], wexcl[16];
    const int tid = threadIdx.x;
    const int lane = tid & 63, wv = tid >> 6;
    const int dir = (blockIdx.x >= NG) ? 1 : 0;
    const int b = blockIdx.x - dir * NG;
    const int*  bb  = dir ? bbC  : bbR;
    const int2* bin = dir ? binC : binR;
    int2*       ed  = dir ? edC  : edR;
    unsigned short* ost = dir ? ostC : ostR;
    const int ebase = bb[b];
    const int eend  = bb[b + 1];
    for (int i = tid; i < BINS; i += 1024) cnt[i] = 0;
    __syncthreads();
    for (int i = ebase + tid; i < eend; i += 1024) {
        const int x = bin[i].x;
        atomicAdd(&cnt[((x >> 18) & 255) * NPH + ((x & 0x3FFFF) >> 12)], 1);
    }
    __syncthreads();
    // exclusive scan over BINS: 10 bins/thread serial + block scan
    int loc[10];
    int s = 0;
    #pragma unroll
    for (int k = 0; k < 10; ++k) {
        const int idx = tid * 10 + k;
        const int v = (idx < BINS) ? cnt[idx] : 0;
        loc[k] = s; s += v;
    }
    int ps = s;
    #pragma unroll
    for (int off = 1; off < 64; off <<= 1) { int t = __shfl_up(ps, off); if (lane >= off) ps += t; }
    if (lane == 63) wtot[wv] = ps;
    __syncthreads();
    if (tid == 0) { int run = 0; for (int w = 0; w < 16; ++w) { wexcl[w] = run; run += wtot[w]; } }
    __syncthreads();
    const int base = wexcl[wv] + (ps - s);
    __syncthreads();
    #pragma unroll
    for (int k = 0; k < 10; ++k) {
        const int idx = tid * 10 + k;
        if (idx < BINS) cnt[idx] = base + loc[k];
    }
    __syncthreads();
    if (tid < RPG) ost[b * RPG + tid] = (unsigned short)cnt[tid * NPH];
    __syncthreads();
    for (int i = ebase + tid; i < eend; i += 1024) {
        const int2 edv = bin[i];
        const int key = ((edv.x >> 18) & 255) * NPH + ((edv.x & 0x3FFFF) >> 12);
        const int pos = ebase + atomicAdd(&cnt[key], 1);
        ed[pos] = edv;
    }
}

// ---------- ego fp32 -> fp16 full-row (128B rows) ----------
__global__ __launch_bounds__(256) void k_cvt(const float4* __restrict__ x,
                                             int4* __restrict__ y) {
    const int i = blockIdx.x * 256 + threadIdx.x;   // over NTOT*8 int4 units
    if (i >= NTOT * 8) return;
    const int r = i >> 3, ch = i & 7;
    const float4 f0 = x[r * 16 + ch * 2];
    const float4 f1 = x[r * 16 + ch * 2 + 1];
    int4 o;
    __half2* oh = (__half2*)&o;
    oh[0] = __floats2half2_rn(f0.x, f0.y);
    oh[1] = __floats2half2_rn(f0.z, f0.w);
    oh[2] = __floats2half2_rn(f1.x, f1.y);
    oh[3] = __floats2half2_rn(f1.z, f1.w);
    y[i] = o;
}

// ---------- register-pull SpMM, quantile-paced phase sweep ----------
// MODE 0: plain -> half; MODE 1: LeakyReLU(0.5) -> half; MODE 2: x(1/64) -> half
#define FMA16(QA, QB, W) { \
    const __half2* h2a = (const __half2*)&(QA); \
    const __half2* h2b = (const __half2*)&(QB); \
    _Pragma("unroll") \
    for (int k = 0; k < 4; ++k) { \
        const float2 fa = __half22float2(h2a[k]); \
        a[2 * k]     = fmaf((W), fa.x, a[2 * k]); \
        a[2 * k + 1] = fmaf((W), fa.y, a[2 * k + 1]); \
        const float2 fb = __half22float2(h2b[k]); \
        a[8 + 2 * k]     = fmaf((W), fb.x, a[8 + 2 * k]); \
        a[8 + 2 * k + 1] = fmaf((W), fb.y, a[8 + 2 * k + 1]); \
    } }

template <int MODE>
__global__ __launch_bounds__(1024) void k_spmm_r(const int* __restrict__ bb,
                                                 const unsigned short* __restrict__ ost,
                                                 const int2* __restrict__ edges,
                                                 const int4* __restrict__ X,
                                                 int4* __restrict__ Y) {
    const int tid = threadIdx.x;
    const int o  = tid & 255;           // owner row within group
    const int c2 = tid >> 8;            // dim chunk (16 dims = 2 int4)
    const int gb = blockIdx.x;
    const int gbase = bb[gb];
    const int s = gbase + ost[gb * RPG + o];
    const int e = (o == 255) ? bb[gb + 1] : gbase + ost[gb * RPG + o + 1];
    const int deg = e - s;
    float a[16];
    #pragma unroll
    for (int k = 0; k < 16; ++k) a[k] = 0.f;
    int i = s;
    // quantile-paced sweep: at step j every lane is at fraction j/32 of its
    // phase-sorted list -> lanes/waves/blocks share one small phase window.
    #pragma unroll 1
    for (int j = 1; j <= 32; ++j) {
        const int nxt = s + ((deg * j) >> 5);
        for (; i + 2 <= nxt; i += 2) {
            const int2 u0 = edges[i];
            const int2 u1 = edges[i + 1];
            const int  s0 = u0.x & 0x3FFFF;
            const int  s1 = u1.x & 0x3FFFF;
            const float w0 = __int_as_float(u0.y);
            const float w1 = __int_as_float(u1.y);
            const int4 qa0 = X[s0 * 8 + c2 * 2];
            const int4 qb0 = X[s0 * 8 + c2 * 2 + 1];
            const int4 qa1 = X[s1 * 8 + c2 * 2];
            const int4 qb1 = X[s1 * 8 + c2 * 2 + 1];
            FMA16(qa0, qb0, w0);
            FMA16(qa1, qb1, w1);
        }
        if (i < nxt) {
            const int2 u = edges[i];
            const int  s0 = u.x & 0x3FFFF;
            const float w0 = __int_as_float(u.y);
            const int4 qa = X[s0 * 8 + c2 * 2];
            const int4 qb = X[s0 * 8 + c2 * 2 + 1];
            FMA16(qa, qb, w0);
            ++i;
        }
    }
    if (MODE == 1) {
        #pragma unroll
        for (int k = 0; k < 16; ++k) a[k] = a[k] > 0.f ? a[k] : 0.5f * a[k];
    }
    if (MODE == 2) {
        #pragma unroll
        for (int k = 0; k < 16; ++k) a[k] *= 0.015625f;   // LN-invariant prescale
    }
    const int row = gb * RPG + o;
    if (row < NTOT) {
        int4 o0, o1;
        __half2* oh0 = (__half2*)&o0;
        __half2* oh1 = (__half2*)&o1;
        #pragma unroll
        for (int k = 0; k < 4; ++k) {
            oh0[k] = __floats2half2_rn(a[2 * k], a[2 * k + 1]);
            oh1[k] = __floats2half2_rn(a[8 + 2 * k], a[8 + 2 * k + 1]);
        }
        __builtin_nontemporal_store(*(const nt_i4*)&o0, (nt_i4*)(Y + (size_t)row * 8 + c2 * 2));
        __builtin_nontemporal_store(*(const nt_i4*)&o1, (nt_i4*)(Y + (size_t)row * 8 + c2 * 2 + 1));
    }
}

// ---------- LN + residual on fp16 full-row z (z prescaled by 1/64) ----------
__global__ __launch_bounds__(256) void k_lnz(const int4* __restrict__ z,
                                             const float* __restrict__ gamma,
                                             const float* __restrict__ beta,
                                             const float* __restrict__ ego,
                                             float* __restrict__ out) {
    const int tid = threadIdx.x;
    const int ch = tid & 7;
    const int r = blockIdx.x * 32 + (tid >> 3);
    if (r >= NTOT) return;
    const int4 zq = z[(size_t)r * 8 + ch];
    const __half2* h = (const __half2*)&zq;
    float f[8];
    #pragma unroll
    for (int k = 0; k < 4; ++k) {
        const float2 t = __half22float2(h[k]);
        f[2 * k] = t.x; f[2 * k + 1] = t.y;
    }
    float s1 = 0.f;
    #pragma unroll
    for (int k = 0; k < 8; ++k) s1 += f[k];
    #pragma unroll
    for (int off = 1; off < 8; off <<= 1) s1 += __shfl_xor(s1, off);
    const float mu = s1 * (1.f / 64.f);
    float q2 = 0.f;
    #pragma unroll
    for (int k = 0; k < 8; ++k) { f[k] -= mu; q2 += f[k] * f[k]; }
    #pragma unroll
    for (int off = 1; off < 8; off <<= 1) q2 += __shfl_xor(q2, off);
    const float rs = rsqrtf(q2 * (1.f / 64.f) + 2.44140625e-09f);  // eps*(1/64)^2
    const float4* g4 = (const float4*)gamma;
    const float4* b4 = (const float4*)beta;
    const float4* e4 = (const float4*)ego + (size_t)r * 16;
    float4*       o4 = (float4*)out + (size_t)r * 16;
    #pragma unroll
    for (int half = 0; half < 2; ++half) {
        const float4 gg = g4[ch * 2 + half];
        const float4 bbv = b4[ch * 2 + half];
        const float4 ee = e4[ch * 2 + half];
        float4 o;
        o.x = f[4 * half + 0] * rs * gg.x + bbv.x + ee.x;
        o.y = f[4 * half + 1] * rs * gg.y + bbv.y + ee.y;
        o.z = f[4 * half + 2] * rs * gg.z + bbv.z + ee.z;
        o.w = f[4 * half + 3] * rs * gg.w + bbv.w + ee.w;
        o4[ch * 2 + half] = o;
    }
}

// ---------- fallback: atomic push (only if ws too small) ----------
__global__ __launch_bounds__(256) void k_push(const int* __restrict__ src_idx,
                                              const int* __restrict__ dst_idx,
                                              const float* __restrict__ vals,
                                              const float* __restrict__ x,
                                              float* __restrict__ y) {
    int gid  = blockIdx.x * 256 + threadIdx.x;
    int e    = gid >> 6;
    int lane = gid & 63;
    if (e >= NE) return;
    atomicAdd(&y[dst_idx[e] * DD + lane], vals[e] * x[src_idx[e] * DD + lane]);
}

__global__ __launch_bounds__(256) void k_leaky(float* __restrict__ x, int n) {
    int i = blockIdx.x * 256 + threadIdx.x;
    if (i < n) { float v = x[i]; x[i] = v > 0.f ? v : 0.5f * v; }
}

__global__ __launch_bounds__(256) void k_lnf(const float* __restrict__ z,
                                             const float* __restrict__ gamma,
                                             const float* __restrict__ beta,
                                             const float* __restrict__ ego,
                                             float* __restrict__ out) {
    int gid  = blockIdx.x * 256 + threadIdx.x;
    int wid  = gid >> 6;
    int lane = threadIdx.x & 63;
    if (wid >= NTOT) return;
    float v = z[wid * DD + lane];
    float sum = v;
    #pragma unroll
    for (int off = 32; off; off >>= 1) sum += __shfl_xor(sum, off);
    float mu = sum * (1.f / 64.f);
    float d  = v - mu;
    float vs = d * d;
    #pragma unroll
    for (int off = 32; off; off >>= 1) vs += __shfl_xor(vs, off);
    float rs = rsqrtf(vs * (1.f / 64.f) + 1e-5f);
    out[wid * DD + lane] = d * rs * gamma[lane] + beta[lane] + ego[wid * DD + lane];
}

extern "C" void kernel_launch(void* const* d_in, const int* in_sizes, int n_in,
                              void* d_out, int out_size, void* d_ws, size_t ws_size,
                              hipStream_t stream) {
    const float* ego   = (const float*)d_in[0];
    const float* vals  = (const float*)d_in[1];
    const float* gamma = (const float*)d_in[2];
    const float* beta  = (const float*)d_in[3];
    const int*   rows  = (const int*)d_in[4];
    const int*   cols  = (const int*)d_in[5];
    float* out = (float*)d_out;

    const size_t SEG  = (size_t)NE * 8;            // 38,400,000 (region stride)
    const size_t BBB  = (size_t)(NG + 1) * 4;      // 2,348
    const size_t OSTB = (size_t)NG * RPG * 2;      // 300,032 (ushort owner starts)
    const size_t NEED = 3 * SEG + 2 * BBB + 2 * OSTB;  // 115,804,760

    if (ws_size >= NEED) {
        char* w = (char*)d_ws;
        int2* edR  = (int2*)w;                     // SEG0: sorted R edges (38.4MB)
        int2* edC  = (int2*)(w + SEG);             // SEG1: sorted C edges
        int2* binR = (int2*)(w + 2 * SEG);         // SEG2: bin scratch R
        int2* binC = (int2*)d_out;                 // d_out: bin scratch C
        int* histR = (int*)w;                      // aliases edR (dead until sortp)
        int* histC = (int*)(w + SEG);              // aliases edC
        int* bbR   = (int*)(w + 3 * SEG);
        int* bbC   = (int*)(w + 3 * SEG + BBB);
        unsigned short* ostR = (unsigned short*)(w + 3 * SEG + 2 * BBB);
        unsigned short* ostC = (unsigned short*)(w + 3 * SEG + 2 * BBB + OSTB);
        // fp16 feature tables (19.2MB each) alias dead binR region after build
        int4* B1 = (int4*)(w + 2 * SEG);
        int4* B2 = (int4*)(w + 2 * SEG + SEG / 2);
        int4* EG = (int4*)d_out;                   // ego fp16 over dead binC

        k_hist <<<NBLK, 256, 0, stream>>>(rows, cols, histR, histC);
        k_scan2<<<2, 1024, 0, stream>>>(histR, histC, bbR, bbC);
        k_bin  <<<NBLK, 256, 0, stream>>>(rows, cols, vals, histR, histC, binR, binC);
        k_sortp<<<2 * NG, 1024, 0, stream>>>(bbR, binR, edR, ostR, bbC, binC, edC, ostC);
        k_cvt  <<<(NTOT * 8 + 255) / 256, 256, 0, stream>>>((const float4*)ego, EG);

        k_spmm_r<0><<<NG, 1024, 0, stream>>>(bbC, ostC, edC, EG, B1);   // A^T e0
        k_spmm_r<1><<<NG, 1024, 0, stream>>>(bbR, ostR, edR, B1, B2);   // leaky(A t)
        k_spmm_r<0><<<NG, 1024, 0, stream>>>(bbC, ostC, edC, B2, B1);
        k_spmm_r<1><<<NG, 1024, 0, stream>>>(bbR, ostR, edR, B1, B2);
        k_spmm_r<0><<<NG, 1024, 0, stream>>>(bbC, ostC, edC, B2, B1);
        k_spmm_r<2><<<NG, 1024, 0, stream>>>(bbR, ostR, edR, B1, B2);   // z/64 -> fp16
        k_lnz  <<<(NTOT + 31) / 32, 256, 0, stream>>>(B2, gamma, beta, ego, out);
    } else {
        const size_t FEAT_BYTES = (size_t)NTOT * DD * 4;
        float* B1 = (float*)d_ws;
        float* B2 = out;
        const int GRID_P = NE / 4;
        const int GRID_N = (NTOT * DD) / 256;
        const float* e = ego;
        for (int layer = 0; layer < 3; ++layer) {
            hipMemsetAsync(B1, 0, FEAT_BYTES, stream);
            k_push<<<GRID_P, 256, 0, stream>>>(rows, cols, vals, e, B1);
            hipMemsetAsync(B2, 0, FEAT_BYTES, stream);
            k_push<<<GRID_P, 256, 0, stream>>>(cols, rows, vals, B1, B2);
            if (layer < 2) {
                k_leaky<<<GRID_N, 256, 0, stream>>>(B2, NTOT * DD);
                e = B2;
            } else {
                k_lnf<<<GRID_N, 256, 0, stream>>>(B2, gamma, beta, ego, out);
            }
        }
    }
}

// Round 9
// 1976.883 us; speedup vs baseline: 4.9860x; 1.5591x over previous
//
#include <hip/hip_runtime.h>
#include <hip/hip_fp16.h>

// HGNN: 3 layers of e = act(A @ (A^T @ e)), N=150000, E=4.8M, D=64.
// Synthesis of measured-good mechanisms:
//  - register accumulation (r6/7: LDS atomics are a 0.32 op/cyc/CU wall)
//  - 4-lane-group coalesced gathers: thread=(row o=tid>>2, chunk c2=tid&3);
//    the 4 lanes fetch the full 128B fp16 source row in one transaction ->
//    hard cap of ONE line fetch per edge visit (r0 structure).
//  - barrier-synced phase sweep (r5: FETCH 262MB measured): per group,
//    edges sorted by (row, src>>13) (19 phases of ~1MB); per-row phase
//    boundaries in a ushort table; __syncthreads() per phase keeps every
//    wave in the block inside the same ~1MB L2-resident gather window.
//  - 4B packed edges (r1-4: absmax unchanged 0.03125): src(18b)|val q14.
// Final layer: x1/64 prescale (LN scale-invariant; avoids fp16 overflow
// of z~1.4e5) -> fp16 z -> LN+residual kernel.

#define NTOT 150000
#define NE   4800000
#define DD   64
#define NG   586            // destination groups (256 rows each; 586*256=150016)
#define RPG  256
#define NBLK 512            // build blocks
#define EPB  9375           // edges per build block
#define NPH  19             // source phases (src>>13, 150000>>13 = 18)
#define BINS (RPG * NPH)    // 4864 sort bins per group
#define PBW  (NPH + 1)      // boundaries per row

typedef int nt_i4 __attribute__((ext_vector_type(4)));

// ---------- phase 1: per-block group histogram (no global atomics) ----------
__global__ __launch_bounds__(256) void k_hist(const int* __restrict__ rows,
                                              const int* __restrict__ cols,
                                              int* __restrict__ histR,
                                              int* __restrict__ histC) {
    __shared__ int hR[NG], hC[NG];
    const int tid = threadIdx.x, blk = blockIdx.x;
    for (int i = tid; i < NG; i += 256) { hR[i] = 0; hC[i] = 0; }
    __syncthreads();
    const int e0 = blk * EPB;
    const int e1 = min(NE, e0 + EPB);
    for (int e = e0 + tid; e < e1; e += 256) {
        atomicAdd(&hR[rows[e] >> 8], 1);
        atomicAdd(&hC[cols[e] >> 8], 1);
    }
    __syncthreads();
    for (int i = tid; i < NG; i += 256) {
        histR[i * NBLK + blk] = hR[i];
        histC[i * NBLK + blk] = hC[i];
    }
}

// ---------- phase 2: exclusive scan of [group][block] + group bounds ----------
__global__ __launch_bounds__(1024) void k_scan2(int* __restrict__ hR, int* __restrict__ hC,
                                                int* __restrict__ bbR, int* __restrict__ bbC) {
    __shared__ int wtot[16], wexcl[16];
    __shared__ int ctot;
    int* a  = blockIdx.x ? hC  : hR;
    int* bb = blockIdx.x ? bbC : bbR;
    const int n = NG * NBLK;
    const int tid  = threadIdx.x;
    const int lane = tid & 63, wv = tid >> 6;
    int carry = 0;
    for (int base = 0; base < n; base += 1024) {
        const int i = base + tid;
        const int v = (i < n) ? a[i] : 0;
        int s = v;
        #pragma unroll
        for (int off = 1; off < 64; off <<= 1) {
            int t = __shfl_up(s, off);
            if (lane >= off) s += t;
        }
        if (lane == 63) wtot[wv] = s;
        __syncthreads();
        if (tid == 0) {
            int run = 0;
            #pragma unroll
            for (int w = 0; w < 16; ++w) { wexcl[w] = run; run += wtot[w]; }
            ctot = run;
        }
        __syncthreads();
        if (i < n) a[i] = carry + wexcl[wv] + (s - v);
        carry += ctot;
        __syncthreads();
    }
    for (int i = tid; i <= NG; i += 1024) bb[i] = (i < NG) ? a[i * NBLK] : NE;
}

// ---------- phase 3: bin edges into group-contiguous ranges ----------
__global__ __launch_bounds__(256) void k_bin(const int* __restrict__ rows,
                                             const int* __restrict__ cols,
                                             const float* __restrict__ vals,
                                             const int* __restrict__ histR,
                                             const int* __restrict__ histC,
                                             int2* __restrict__ binR,
                                             int2* __restrict__ binC) {
    __shared__ int cR[NG], cC[NG];
    const int tid = threadIdx.x, blk = blockIdx.x;
    for (int i = tid; i < NG; i += 256) {
        cR[i] = histR[i * NBLK + blk];
        cC[i] = histC[i * NBLK + blk];
    }
    __syncthreads();
    const int e0 = blk * EPB;
    const int e1 = min(NE, e0 + EPB);
    for (int e = e0 + tid; e < e1; e += 256) {
        const int r = rows[e], c = cols[e];
        const int vb = __float_as_int(vals[e]);
        int p = atomicAdd(&cR[r >> 8], 1);
        int2 pr; pr.x = ((r & 255) << 18) | c; pr.y = vb;   // local dst | src
        binR[p] = pr;
        int q = atomicAdd(&cC[c >> 8], 1);
        int2 pc; pc.x = ((c & 255) << 18) | r; pc.y = vb;
        binC[q] = pc;
    }
}

// ---------- phase 4: per-group sort by (row, src phase); pack edges to 4B;
// ----------          emit per-row phase-boundary table (ushort) ----------
__global__ __launch_bounds__(1024) void k_sortp(const int* __restrict__ bbR,
                                                const int2* __restrict__ binR,
                                                unsigned int* __restrict__ edR,
                                                unsigned short* __restrict__ pbtR,
                                                const int* __restrict__ bbC,
                                                const int2* __restrict__ binC,
                                                unsigned int* __restrict__ edC,
                                                unsigned short* __restrict__ pbtC) {
    __shared__ int cnt[BINS];
    __shared__ int wtot[16], wexcl[16];
    const int tid = threadIdx.x;
    const int lane = tid & 63, wv = tid >> 6;
    const int dir = (blockIdx.x >= NG) ? 1 : 0;
    const int b = blockIdx.x - dir * NG;
    const int*  bb  = dir ? bbC  : bbR;
    const int2* bin = dir ? binC : binR;
    unsigned int*   ed  = dir ? edC  : edR;
    unsigned short* pbt = dir ? pbtC : pbtR;
    const int ebase = bb[b];
    const int eend  = bb[b + 1];
    const int gsize = eend - ebase;
    for (int i = tid; i < BINS; i += 1024) cnt[i] = 0;
    __syncthreads();
    for (int i = ebase + tid; i < eend; i += 1024) {
        const int x = bin[i].x;
        atomicAdd(&cnt[((x >> 18) & 255) * NPH + ((x & 0x3FFFF) >> 13)], 1);
    }
    __syncthreads();
    // exclusive scan over BINS: 5 bins/thread serial + block scan
    int loc[5];
    int s = 0;
    #pragma unroll
    for (int k = 0; k < 5; ++k) {
        const int idx = tid * 5 + k;
        const int v = (idx < BINS) ? cnt[idx] : 0;
        loc[k] = s; s += v;
    }
    int ps = s;
    #pragma unroll
    for (int off = 1; off < 64; off <<= 1) { int t = __shfl_up(ps, off); if (lane >= off) ps += t; }
    if (lane == 63) wtot[wv] = ps;
    __syncthreads();
    if (tid == 0) { int run = 0; for (int w = 0; w < 16; ++w) { wexcl[w] = run; run += wtot[w]; } }
    __syncthreads();
    const int base = wexcl[wv] + (ps - s);
    __syncthreads();
    #pragma unroll
    for (int k = 0; k < 5; ++k) {
        const int idx = tid * 5 + k;
        if (idx < BINS) cnt[idx] = base + loc[k];
    }
    __syncthreads();
    // per-row phase boundaries: 256 rows x 20 entries = 5120 = 1024*5 exactly
    #pragma unroll
    for (int k = 0; k < 5; ++k) {
        const int idx = tid * 5 + k;
        const int oo = idx / PBW, p = idx - oo * PBW;
        int v;
        if (p < NPH)        v = cnt[oo * NPH + p];
        else if (oo < 255)  v = cnt[(oo + 1) * NPH];
        else                v = gsize;
        pbt[((size_t)b * RPG + oo) * PBW + p] = (unsigned short)v;
    }
    __syncthreads();
    // scatter with 4B packing: src(18b) | q14 val
    for (int i = ebase + tid; i < eend; i += 1024) {
        const int2 edv = bin[i];
        const int key = ((edv.x >> 18) & 255) * NPH + ((edv.x & 0x3FFFF) >> 13);
        const int pos = ebase + atomicAdd(&cnt[key], 1);
        int qv = (int)(__int_as_float(edv.y) * 16384.f);
        qv = qv > 16383 ? 16383 : qv;
        ed[pos] = ((unsigned)edv.x & 0x3FFFFu) | ((unsigned)qv << 18);
    }
}

// ---------- ego fp32 -> fp16 full-row (128B rows) ----------
__global__ __launch_bounds__(256) void k_cvt(const float4* __restrict__ x,
                                             int4* __restrict__ y) {
    const int i = blockIdx.x * 256 + threadIdx.x;   // over NTOT*8 int4 units
    if (i >= NTOT * 8) return;
    const int r = i >> 3, ch = i & 7;
    const float4 f0 = x[r * 16 + ch * 2];
    const float4 f1 = x[r * 16 + ch * 2 + 1];
    int4 o;
    __half2* oh = (__half2*)&o;
    oh[0] = __floats2half2_rn(f0.x, f0.y);
    oh[1] = __floats2half2_rn(f0.z, f0.w);
    oh[2] = __floats2half2_rn(f1.x, f1.y);
    oh[3] = __floats2half2_rn(f1.z, f1.w);
    y[i] = o;
}

// ---------- phase-swept register-pull SpMM, 4-lane coalesced gathers ----------
// MODE 0: plain -> half; MODE 1: LeakyReLU(0.5) -> half; MODE 2: x(1/64) -> half
template <int MODE>
__global__ __launch_bounds__(1024) void k_spmm_p(const int* __restrict__ bb,
                                                 const unsigned short* __restrict__ pbt,
                                                 const unsigned int* __restrict__ edges,
                                                 const int4* __restrict__ X,
                                                 int4* __restrict__ Y) {
    const int tid = threadIdx.x;
    const int o  = tid >> 2;            // owner row within group (0..255)
    const int c2 = tid & 3;             // 32B chunk within 128B row
    const int gb = blockIdx.x;
    const int gbase = bb[gb];
    const unsigned short* pb = pbt + ((size_t)gb * RPG + o) * PBW;
    float a[16];
    #pragma unroll
    for (int k = 0; k < 16; ++k) a[k] = 0.f;
    int i = gbase + pb[0];
    #pragma unroll 1
    for (int p = 1; p <= NPH; ++p) {
        const int stop = gbase + pb[p];
        for (; i < stop; ++i) {
            const unsigned u = __builtin_nontemporal_load(edges + i);
            const int   s0 = (int)(u & 0x3FFFFu);
            const float w  = (float)(u >> 18) * 6.103515625e-05f;
            const int4 qa = X[s0 * 8 + c2 * 2];
            const int4 qb = X[s0 * 8 + c2 * 2 + 1];
            const __half2* h2a = (const __half2*)&qa;
            const __half2* h2b = (const __half2*)&qb;
            #pragma unroll
            for (int k = 0; k < 4; ++k) {
                const float2 fa = __half22float2(h2a[k]);
                a[2 * k]     = fmaf(w, fa.x, a[2 * k]);
                a[2 * k + 1] = fmaf(w, fa.y, a[2 * k + 1]);
                const float2 fb = __half22float2(h2b[k]);
                a[8 + 2 * k]     = fmaf(w, fb.x, a[8 + 2 * k]);
                a[8 + 2 * k + 1] = fmaf(w, fb.y, a[8 + 2 * k + 1]);
            }
        }
        __syncthreads();   // pin all waves of the block to the same phase window
    }
    if (MODE == 1) {
        #pragma unroll
        for (int k = 0; k < 16; ++k) a[k] = a[k] > 0.f ? a[k] : 0.5f * a[k];
    }
    if (MODE == 2) {
        #pragma unroll
        for (int k = 0; k < 16; ++k) a[k] *= 0.015625f;   // LN-invariant prescale
    }
    const int row = gb * RPG + o;
    if (row < NTOT) {
        int4 o0, o1;
        __half2* oh0 = (__half2*)&o0;
        __half2* oh1 = (__half2*)&o1;
        #pragma unroll
        for (int k = 0; k < 4; ++k) {
            oh0[k] = __floats2half2_rn(a[2 * k], a[2 * k + 1]);
            oh1[k] = __floats2half2_rn(a[8 + 2 * k], a[8 + 2 * k + 1]);
        }
        __builtin_nontemporal_store(*(const nt_i4*)&o0, (nt_i4*)(Y + (size_t)row * 8 + c2 * 2));
        __builtin_nontemporal_store(*(const nt_i4*)&o1, (nt_i4*)(Y + (size_t)row * 8 + c2 * 2 + 1));
    }
}

// ---------- LN + residual on fp16 full-row z (z prescaled by 1/64) ----------
__global__ __launch_bounds__(256) void k_lnz(const int4* __restrict__ z,
                                             const float* __restrict__ gamma,
                                             const float* __restrict__ beta,
                                             const float* __restrict__ ego,
                                             float* __restrict__ out) {
    const int tid = threadIdx.x;
    const int ch = tid & 7;
    const int r = blockIdx.x * 32 + (tid >> 3);
    if (r >= NTOT) return;
    const int4 zq = z[(size_t)r * 8 + ch];
    const __half2* h = (const __half2*)&zq;
    float f[8];
    #pragma unroll
    for (int k = 0; k < 4; ++k) {
        const float2 t = __half22float2(h[k]);
        f[2 * k] = t.x; f[2 * k + 1] = t.y;
    }
    float s1 = 0.f;
    #pragma unroll
    for (int k = 0; k < 8; ++k) s1 += f[k];
    #pragma unroll
    for (int off = 1; off < 8; off <<= 1) s1 += __shfl_xor(s1, off);
    const float mu = s1 * (1.f / 64.f);
    float q2 = 0.f;
    #pragma unroll
    for (int k = 0; k < 8; ++k) { f[k] -= mu; q2 += f[k] * f[k]; }
    #pragma unroll
    for (int off = 1; off < 8; off <<= 1) q2 += __shfl_xor(q2, off);
    const float rs = rsqrtf(q2 * (1.f / 64.f) + 2.44140625e-09f);  // eps*(1/64)^2
    const float4* g4 = (const float4*)gamma;
    const float4* b4 = (const float4*)beta;
    const float4* e4 = (const float4*)ego + (size_t)r * 16;
    float4*       o4 = (float4*)out + (size_t)r * 16;
    #pragma unroll
    for (int half = 0; half < 2; ++half) {
        const float4 gg = g4[ch * 2 + half];
        const float4 bbv = b4[ch * 2 + half];
        const float4 ee = e4[ch * 2 + half];
        float4 o;
        o.x = f[4 * half + 0] * rs * gg.x + bbv.x + ee.x;
        o.y = f[4 * half + 1] * rs * gg.y + bbv.y + ee.y;
        o.z = f[4 * half + 2] * rs * gg.z + bbv.z + ee.z;
        o.w = f[4 * half + 3] * rs * gg.w + bbv.w + ee.w;
        o4[ch * 2 + half] = o;
    }
}

// ---------- fallback: atomic push (only if ws too small) ----------
__global__ __launch_bounds__(256) void k_push(const int* __restrict__ src_idx,
                                              const int* __restrict__ dst_idx,
                                              const float* __restrict__ vals,
                                              const float* __restrict__ x,
                                              float* __restrict__ y) {
    int gid  = blockIdx.x * 256 + threadIdx.x;
    int e    = gid >> 6;
    int lane = gid & 63;
    if (e >= NE) return;
    atomicAdd(&y[dst_idx[e] * DD + lane], vals[e] * x[src_idx[e] * DD + lane]);
}

__global__ __launch_bounds__(256) void k_leaky(float* __restrict__ x, int n) {
    int i = blockIdx.x * 256 + threadIdx.x;
    if (i < n) { float v = x[i]; x[i] = v > 0.f ? v : 0.5f * v; }
}

__global__ __launch_bounds__(256) void k_lnf(const float* __restrict__ z,
                                             const float* __restrict__ gamma,
                                             const float* __restrict__ beta,
                                             const float* __restrict__ ego,
                                             float* __restrict__ out) {
    int gid  = blockIdx.x * 256 + threadIdx.x;
    int wid  = gid >> 6;
    int lane = threadIdx.x & 63;
    if (wid >= NTOT) return;
    float v = z[wid * DD + lane];
    float sum = v;
    #pragma unroll
    for (int off = 32; off; off >>= 1) sum += __shfl_xor(sum, off);
    float mu = sum * (1.f / 64.f);
    float d  = v - mu;
    float vs = d * d;
    #pragma unroll
    for (int off = 32; off; off >>= 1) vs += __shfl_xor(vs, off);
    float rs = rsqrtf(vs * (1.f / 64.f) + 1e-5f);
    out[wid * DD + lane] = d * rs * gamma[lane] + beta[lane] + ego[wid * DD + lane];
}

extern "C" void kernel_launch(void* const* d_in, const int* in_sizes, int n_in,
                              void* d_out, int out_size, void* d_ws, size_t ws_size,
                              hipStream_t stream) {
    const float* ego   = (const float*)d_in[0];
    const float* vals  = (const float*)d_in[1];
    const float* gamma = (const float*)d_in[2];
    const float* beta  = (const float*)d_in[3];
    const int*   rows  = (const int*)d_in[4];
    const int*   cols  = (const int*)d_in[5];
    float* out = (float*)d_out;

    const size_t SEG   = (size_t)NE * 8;                 // 38,400,000
    const size_t EDB   = (size_t)NE * 4;                 // 19,200,000 packed edges
    const size_t PBTB  = (size_t)NG * RPG * PBW * 2;     // 6,000,640
    const size_t HISTB = (size_t)NG * NBLK * 4;          // 1,200,128
    const size_t BBB   = (size_t)(NG + 1) * 4;           // 2,348
    const size_t NEED  = SEG + 2 * EDB + 2 * PBTB + 2 * HISTB + 2 * BBB;

    if (ws_size >= NEED) {
        char* w = (char*)d_ws;
        int2* binR = (int2*)w;                           // [0, 38.4M) build scratch
        int2* binC = (int2*)d_out;                       // d_out as scratch pre-output
        unsigned int* edR = (unsigned int*)(w + SEG);
        unsigned int* edC = (unsigned int*)(w + SEG + EDB);
        unsigned short* pbtR = (unsigned short*)(w + SEG + 2 * EDB);
        unsigned short* pbtC = (unsigned short*)(w + SEG + 2 * EDB + PBTB);
        int* histR = (int*)(w + SEG + 2 * EDB + 2 * PBTB);
        int* histC = (int*)(w + SEG + 2 * EDB + 2 * PBTB + HISTB);
        int* bbR   = (int*)(w + SEG + 2 * EDB + 2 * PBTB + 2 * HISTB);
        int* bbC   = (int*)(w + SEG + 2 * EDB + 2 * PBTB + 2 * HISTB + BBB);
        // fp16 feature tables (19.2MB each) alias dead binR region after build
        int4* B1 = (int4*)w;
        int4* B2 = (int4*)(w + EDB);
        int4* EG = (int4*)d_out;                         // ego fp16 over dead binC

        k_hist <<<NBLK, 256, 0, stream>>>(rows, cols, histR, histC);
        k_scan2<<<2, 1024, 0, stream>>>(histR, histC, bbR, bbC);
        k_bin  <<<NBLK, 256, 0, stream>>>(rows, cols, vals, histR, histC, binR, binC);
        k_sortp<<<2 * NG, 1024, 0, stream>>>(bbR, binR, edR, pbtR, bbC, binC, edC, pbtC);
        k_cvt  <<<(NTOT * 8 + 255) / 256, 256, 0, stream>>>((const float4*)ego, EG);

        k_spmm_p<0><<<NG, 1024, 0, stream>>>(bbC, pbtC, edC, EG, B1);   // A^T e0
        k_spmm_p<1><<<NG, 1024, 0, stream>>>(bbR, pbtR, edR, B1, B2);   // leaky(A t)
        k_spmm_p<0><<<NG, 1024, 0, stream>>>(bbC, pbtC, edC, B2, B1);
        k_spmm_p<1><<<NG, 1024, 0, stream>>>(bbR, pbtR, edR, B1, B2);
        k_spmm_p<0><<<NG, 1024, 0, stream>>>(bbC, pbtC, edC, B2, B1);
        k_spmm_p<2><<<NG, 1024, 0, stream>>>(bbR, pbtR, edR, B1, B2);   // z/64 -> fp16
        k_lnz  <<<(NTOT + 31) / 32, 256, 0, stream>>>(B2, gamma, beta, ego, out);
    } else {
        const size_t FEAT_BYTES = (size_t)NTOT * DD * 4;
        float* B1 = (float*)d_ws;
        float* B2 = out;
        const int GRID_P = NE / 4;
        const int GRID_N = (NTOT * DD) / 256;
        const float* e = ego;
        for (int layer = 0; layer < 3; ++layer) {
            hipMemsetAsync(B1, 0, FEAT_BYTES, stream);
            k_push<<<GRID_P, 256, 0, stream>>>(rows, cols, vals, e, B1);
            hipMemsetAsync(B2, 0, FEAT_BYTES, stream);
            k_push<<<GRID_P, 256, 0, stream>>>(cols, rows, vals, B1, B2);
            if (layer < 2) {
                k_leaky<<<GRID_N, 256, 0, stream>>>(B2, NTOT * DD);
                e = B2;
            } else {
                k_lnf<<<GRID_N, 256, 0, stream>>>(B2, gamma, beta, ego, out);
            }
        }
    }
}